// Round 1
// baseline (6761.808 us; speedup 1.0000x reference)
//
#include <hip/hip_runtime.h>
#include <stdint.h>

typedef __bf16 bf16;
typedef __attribute__((ext_vector_type(4))) float f4;
typedef __attribute__((ext_vector_type(4))) float f32x4;
typedef __attribute__((ext_vector_type(8))) __bf16 bf8v;
typedef __attribute__((ext_vector_type(4))) __bf16 bf4v;

#define NN 30000
#define MPAD 30080
#define OUTSTRIDE 15360000  // 30000*512

typedef __attribute__((address_space(3))) unsigned int as3_u32;
typedef __attribute__((address_space(1))) unsigned int as1_u32;

__device__ __forceinline__ void gl_lds16(const void* g, void* l) {
  __builtin_amdgcn_global_load_lds((as1_u32*)g, (as3_u32*)l, 16, 0, 0);
}

// ---------- degree / dinv ----------
__global__ void k_deg_init(float* deg, int n) {
  int i = blockIdx.x * 256 + threadIdx.x;
  if (i < n) deg[i] = 1.0f;  // self-loop weight 1
}

__global__ void k_deg_acc(const int* __restrict__ ei, const float* __restrict__ ew,
                          float* __restrict__ deg, int E) {
  int e = blockIdx.x * 256 + threadIdx.x;
  if (e < E) atomicAdd(&deg[ei[E + e]], ew[e]);
}

__global__ void k_dinv(float* dinv, int n) {
  int i = blockIdx.x * 256 + threadIdx.x;
  if (i < n) { float d = dinv[i]; dinv[i] = d > 0.f ? rsqrtf(d) : 0.f; }
}

// ---------- x -> bf16 ----------
__global__ void k_xbf(const float* __restrict__ x, bf16* __restrict__ xbf, int n8) {
  int i = blockIdx.x * 256 + threadIdx.x;
  if (i >= n8) return;
  const f4* x4 = (const f4*)x;
  f4 a = x4[2 * i], b = x4[2 * i + 1];
  bf8v o;
#pragma unroll
  for (int j = 0; j < 4; ++j) { o[j] = (bf16)a[j]; o[4 + j] = (bf16)b[j]; }
  ((bf8v*)xbf)[i] = o;
}

// ---------- y = dinv^2 * x (self loops) ----------
__global__ void k_yinit(const float* __restrict__ x, const float* __restrict__ dinv,
                        float* __restrict__ y, int n4) {
  int i = blockIdx.x * 256 + threadIdx.x;
  if (i >= n4) return;
  int node = i >> 7;
  float s = dinv[node]; s *= s;
  f4 v = ((const f4*)x)[i];
  ((f4*)y)[i] = v * s;
}

// ---------- edge aggregation: y[dst] += norm * x[src], one wave per edge ----------
__global__ void k_edge(const int* __restrict__ ei, const float* __restrict__ ew,
                       const float* __restrict__ dinv, const bf16* __restrict__ xbf,
                       float* __restrict__ y, int E) {
  int gw = (blockIdx.x * 256 + threadIdx.x) >> 6;
  if (gw >= E) return;
  int lane = threadIdx.x & 63;
  int s = ei[gw], d = ei[E + gw];
  float nrm = dinv[s] * ew[gw] * dinv[d];
  bf8v xv = *(const bf8v*)(xbf + ((size_t)s << 9) + lane * 8);
  float* yd = y + ((size_t)d << 9) + lane * 8;
#pragma unroll
  for (int j = 0; j < 8; ++j) atomicAdd(yd + j, nrm * (float)xv[j]);
}

// ---------- y -> bf16 (padded rows zeroed) ----------
__global__ void k_ybf(const float* __restrict__ y, bf16* __restrict__ ybf, int n8) {
  int i = blockIdx.x * 256 + threadIdx.x;
  if (i >= n8) return;
  int row = i >> 6;
  bf8v o;
  if (row < NN) {
    const f4* y4 = (const f4*)y;
    f4 a = y4[2 * i], b = y4[2 * i + 1];
#pragma unroll
    for (int j = 0; j < 4; ++j) { o[j] = (bf16)a[j]; o[4 + j] = (bf16)b[j]; }
  } else {
#pragma unroll
    for (int j = 0; j < 8; ++j) o[j] = (bf16)0.f;
  }
  ((bf8v*)ybf)[i] = o;
}

// ---------- W_comb precompute: Wt[g][j][k] = sum_c Wc_g[k][c] * Wl_g[c][j] (bf16, transposed) ----------
__global__ void k_wcomb(const float* __restrict__ WcA, const float* __restrict__ WlA,
                        const float* __restrict__ WcB, const float* __restrict__ WlB,
                        const float* __restrict__ WcC, const float* __restrict__ WlC,
                        bf16* __restrict__ Wt) {
  const float* Wc; const float* Wl;
  int g = blockIdx.z;
  if (g == 0)      { Wc = WcA; Wl = WlA; }
  else if (g == 1) { Wc = WcB; Wl = WlB; }
  else             { Wc = WcC; Wl = WlC; }
  int k0 = blockIdx.x * 64, j0 = blockIdx.y * 64;
  int t = threadIdx.x, tx = t & 15, ty = t >> 4;
  __shared__ float sWc[64][17];  // [k][c]
  __shared__ float sWl[16][64];  // [c][j]
  float acc[4][4] = {};
  for (int c0 = 0; c0 < 512; c0 += 16) {
    { int kk = t >> 2, c4 = (t & 3) * 4;
      f4 v = *(const f4*)(Wc + (size_t)(k0 + kk) * 512 + c0 + c4);
#pragma unroll
      for (int j = 0; j < 4; ++j) sWc[kk][c4 + j] = v[j]; }
    { int cc = t >> 4, j4 = (t & 15) * 4;
      f4 v = *(const f4*)(Wl + (size_t)(c0 + cc) * 512 + j0 + j4);
      *(f4*)&sWl[cc][j4] = v; }
    __syncthreads();
#pragma unroll
    for (int cc = 0; cc < 16; ++cc) {
      float wcv[4], wlv[4];
#pragma unroll
      for (int b = 0; b < 4; ++b) wcv[b] = sWc[tx * 4 + b][cc];
#pragma unroll
      for (int a = 0; a < 4; ++a) wlv[a] = sWl[cc][ty * 4 + a];
#pragma unroll
      for (int a = 0; a < 4; ++a)
#pragma unroll
        for (int b = 0; b < 4; ++b) acc[a][b] += wlv[a] * wcv[b];
    }
    __syncthreads();
  }
#pragma unroll
  for (int a = 0; a < 4; ++a) {
    bf4v o;
#pragma unroll
    for (int b = 0; b < 4; ++b) o[b] = (bf16)acc[a][b];
    *(bf4v*)&Wt[((size_t)g * 512 + j0 + ty * 4 + a) * 512 + k0 + tx * 4] = o;
  }
}

// ---------- combined bias: bcomb[g][j] = bl_g[j] + sum_c bc_g[c]*Wl_g[c][j] ----------
__global__ void k_bcomb(const float* __restrict__ bcA, const float* __restrict__ blA,
                        const float* __restrict__ bcB, const float* __restrict__ blB,
                        const float* __restrict__ bcC, const float* __restrict__ blC,
                        float* __restrict__ bcomb) {
  int t = blockIdx.x * 256 + threadIdx.x;
  if (t >= 1536) return;
  int g = t >> 9, j = t & 511;
  const float* bc; const float* bl; const float* Wl = nullptr;
  (void)Wl;
  if (g == 0)      { bc = bcA; bl = blA; }
  else if (g == 1) { bc = bcB; bl = blB; }
  else             { bc = bcC; bl = blC; }
  // Wl pointers are passed interleaved through bc pointers' sibling arrays; recompute:
  bcomb[t] = bl[j] + 0.f;  // bc @ Wl_top added below via second kernel variant
  float s = 0.f;
  // NOTE: we need Wl here; use the trick that bc arrays are tiny and usually zero,
  // but compute exactly: Wl passed via bcomb's upper region is not available, so this
  // kernel is replaced by k_bcomb2 below. (kept for clarity; not launched)
  (void)bc; (void)s;
}

__global__ void k_bcomb2(const float* __restrict__ bcA, const float* __restrict__ blA, const float* __restrict__ WlA,
                         const float* __restrict__ bcB, const float* __restrict__ blB, const float* __restrict__ WlB,
                         const float* __restrict__ bcC, const float* __restrict__ blC, const float* __restrict__ WlC,
                         float* __restrict__ bcomb) {
  int t = blockIdx.x * 256 + threadIdx.x;
  if (t >= 1536) return;
  int g = t >> 9, j = t & 511;
  const float* bc; const float* bl; const float* Wl;
  if (g == 0)      { bc = bcA; bl = blA; Wl = WlA; }
  else if (g == 1) { bc = bcB; bl = blB; Wl = WlB; }
  else             { bc = bcC; bl = blC; Wl = WlC; }
  float s = bl[j];
  for (int c = 0; c < 512; ++c) s += bc[c] * Wl[(size_t)c * 512 + j];
  bcomb[t] = s;
}

// ---------- main fused GEMM: Z = ybf @ Wt^T per gate, epilogue -> O/Hn/Cn ----------
__global__ __launch_bounds__(256) void k_gemm(const bf16* __restrict__ A, const bf16* __restrict__ Bt,
                                              const float* __restrict__ bcomb, float* __restrict__ out) {
  __shared__ __align__(16) char lds[40960];  // A: [0,16384) B: 3 x 8192
  const int t = threadIdx.x, lane = t & 63, w = t >> 6;
  const int wm = w >> 1, wn = w & 1;
  const int m0 = blockIdx.y * 128, n0 = blockIdx.x * 64;
  const int l15 = lane & 15, lhi = lane >> 4;
  f32x4 acc[3][4][2] = {};

  for (int ks = 0; ks < 8; ++ks) {
    const int k0 = ks * 64;
    // stage A tile 128x64 bf16 (16KB), linear dest + pre-swizzled source
#pragma unroll
    for (int it = 0; it < 4; ++it) {
      int P = (((it * 4 + w) << 6) | lane) << 4;  // physical byte in A tile
      int r = P >> 7;
      int wl = (P & 127) ^ ((r & 7) << 4);
      const char* src = (const char*)A + (((size_t)(m0 + r)) << 10) + (k0 << 1) + wl;
      gl_lds16(src, lds + P);
    }
    // stage B tiles: 3 gates x 64x64 bf16 (8KB each), rows are n, cols k
#pragma unroll
    for (int it = 0; it < 6; ++it) {
      int flat = it * 4 + w;          // 0..23
      int g = flat >> 3, q = flat & 7;
      int P = ((q << 6) | lane) << 4; // byte within gate tile
      int n = P >> 7;
      int wl = (P & 127) ^ ((n & 7) << 4);
      const char* src = (const char*)Bt + (((size_t)(g * 512 + n0 + n)) << 10) + (k0 << 1) + wl;
      gl_lds16(src, lds + 16384 + g * 8192 + P);
    }
    asm volatile("s_waitcnt vmcnt(0)" ::: "memory");
    __syncthreads();
#pragma unroll
    for (int kh = 0; kh < 2; ++kh) {
      bf8v af[4];
#pragma unroll
      for (int mi = 0; mi < 4; ++mi) {
        int r = wm * 64 + mi * 16 + l15;
        int off = (kh * 64 + lhi * 16) ^ ((r & 7) << 4);
        af[mi] = *(const bf8v*)(lds + r * 128 + off);
      }
      bf8v bfr[3][2];
#pragma unroll
      for (int g = 0; g < 3; ++g)
#pragma unroll
        for (int ni = 0; ni < 2; ++ni) {
          int n = wn * 32 + ni * 16 + l15;
          int off = (kh * 64 + lhi * 16) ^ ((n & 7) << 4);
          bfr[g][ni] = *(const bf8v*)(lds + 16384 + g * 8192 + n * 128 + off);
        }
#pragma unroll
      for (int g = 0; g < 3; ++g)
#pragma unroll
        for (int mi = 0; mi < 4; ++mi)
#pragma unroll
          for (int ni = 0; ni < 2; ++ni)
            acc[g][mi][ni] = __builtin_amdgcn_mfma_f32_16x16x32_bf16(af[mi], bfr[g][ni], acc[g][mi][ni], 0, 0, 0);
    }
    __syncthreads();
  }

  // epilogue: gates + LSTM combine, write O/Hn/Cn
#pragma unroll
  for (int ni = 0; ni < 2; ++ni) {
    int col = n0 + wn * 32 + ni * 16 + l15;
    float bI = bcomb[col], bG = bcomb[512 + col], bO = bcomb[1024 + col];
#pragma unroll
    for (int mi = 0; mi < 4; ++mi) {
#pragma unroll
      for (int r = 0; r < 4; ++r) {
        int row = m0 + wm * 64 + mi * 16 + lhi * 4 + r;
        if (row < NN) {
          float zi = acc[0][mi][ni][r] + bI;
          float zg = acc[1][mi][ni][r] + bG;
          float zo = acc[2][mi][ni][r] + bO;
          float I = 1.f / (1.f + __expf(-zi));
          float e2g = __expf(2.f * zg);
          float G = (e2g - 1.f) / (e2g + 1.f);
          float O = 1.f / (1.f + __expf(-zo));
          float Cn = I * G;
          float e2c = __expf(2.f * Cn);
          float tc = (e2c - 1.f) / (e2c + 1.f);
          float Hn = O * tc;
          size_t base = ((size_t)row << 9) + col;
          out[base] = O;
          out[OUTSTRIDE + base] = Hn;
          out[2 * OUTSTRIDE + base] = Cn;
        }
      }
    }
  }
}

extern "C" void kernel_launch(void* const* d_in, const int* in_sizes, int n_in,
                              void* d_out, int out_size, void* d_ws, size_t ws_size,
                              hipStream_t stream) {
  const float* x   = (const float*)d_in[0];
  const int*   ei  = (const int*)d_in[1];
  const float* ew  = (const float*)d_in[2];
  const float* Wc_i = (const float*)d_in[3];
  const float* bc_i = (const float*)d_in[4];
  const float* Wl_i = (const float*)d_in[5];
  const float* bl_i = (const float*)d_in[6];
  // F gate (d_in[7..10]) is dead: Cn = F*0 + I*G
  const float* Wc_g = (const float*)d_in[11];
  const float* bc_g = (const float*)d_in[12];
  const float* Wl_g = (const float*)d_in[13];
  const float* bl_g = (const float*)d_in[14];
  const float* Wc_o = (const float*)d_in[15];
  const float* bc_o = (const float*)d_in[16];
  const float* Wl_o = (const float*)d_in[17];
  const float* bl_o = (const float*)d_in[18];

  const int E = in_sizes[2];
  const int n = in_sizes[0] / 512;  // 30000

  // workspace layout
  char* ws = (char*)d_ws;
  bf16*  ybf   = (bf16*)ws;                      // MPAD*512*2  = 30,801,920
  float* dinv  = (float*)(ws + 30801920);        // 120,000
  bf16*  Wt    = (bf16*)(ws + 30924800);         // 3*512*512*2 = 1,572,864
  float* bcomb = (float*)(ws + 32497664);        // 6,144
  (void)ws_size;

  // scratch inside d_out (dead before epilogue writes)
  float* out = (float*)d_out;
  float* y   = out;                               // [0, 61.44MB)
  bf16*  xbf = (bf16*)((char*)d_out + 61440000);  // 30.72MB
  (void)out_size; (void)n_in;

  k_deg_init<<<(n + 255) / 256, 256, 0, stream>>>(dinv, n);
  k_deg_acc<<<(E + 255) / 256, 256, 0, stream>>>(ei, ew, dinv, E);
  k_dinv<<<(n + 255) / 256, 256, 0, stream>>>(dinv, n);
  k_xbf<<<(n * 512 / 8 + 255) / 256, 256, 0, stream>>>(x, xbf, n * 512 / 8);
  k_yinit<<<(n * 128 + 255) / 256, 256, 0, stream>>>(x, dinv, y, n * 128);
  k_edge<<<(E * 64 + 255) / 256, 256, 0, stream>>>(ei, ew, dinv, xbf, y, E);
  k_ybf<<<(MPAD * 64 + 255) / 256, 256, 0, stream>>>(y, ybf, MPAD * 64);
  k_wcomb<<<dim3(8, 8, 3), 256, 0, stream>>>(Wc_i, Wl_i, Wc_g, Wl_g, Wc_o, Wl_o, Wt);
  k_bcomb2<<<6, 256, 0, stream>>>(bc_i, bl_i, Wl_i, bc_g, bl_g, Wl_g, bc_o, bl_o, Wl_o, bcomb);
  k_gemm<<<dim3(8, 235), 256, 0, stream>>>(ybf, Wt, bcomb, out);
}

// Round 2
// 392.850 us; speedup vs baseline: 17.2122x; 17.2122x over previous
//
#include <hip/hip_runtime.h>
#include <stdint.h>

typedef __bf16 bf16;
typedef __attribute__((ext_vector_type(4))) float f4;
typedef __attribute__((ext_vector_type(4))) float f32x4;
typedef __attribute__((ext_vector_type(8))) __bf16 bf8v;
typedef __attribute__((ext_vector_type(4))) __bf16 bf4v;

#define NN 30000
#define MPAD 30080
#define OUTSTRIDE 15360000  // 30000*512

typedef __attribute__((address_space(3))) unsigned int as3_u32;
typedef __attribute__((address_space(1))) unsigned int as1_u32;

__device__ __forceinline__ void gl_lds16(const void* g, void* l) {
  __builtin_amdgcn_global_load_lds((as1_u32*)g, (as3_u32*)l, 16, 0, 0);
}

// ---------- init: deg=1 (self loop), counts=0, cursor=0 ----------
__global__ void k_init(float* deg, int* counts, int* cursor, int n) {
  int i = blockIdx.x * 256 + threadIdx.x;
  if (i < n) { deg[i] = 1.0f; counts[i] = 0; cursor[i] = 0; }
}

// ---------- per-edge: degree accum + dst histogram ----------
__global__ void k_pre(const int* __restrict__ ei, const float* __restrict__ ew,
                      float* __restrict__ deg, int* __restrict__ counts, int E) {
  int e = blockIdx.x * 256 + threadIdx.x;
  if (e < E) {
    int d = ei[E + e];
    atomicAdd(&deg[d], ew[e]);
    atomicAdd(&counts[d], 1);
  }
}

__global__ void k_dinv(float* dinv, int n) {
  int i = blockIdx.x * 256 + threadIdx.x;
  if (i < n) { float d = dinv[i]; dinv[i] = d > 0.f ? rsqrtf(d) : 0.f; }
}

// ---------- exclusive scan of counts -> offs (single block, sequential chunks) ----------
__global__ __launch_bounds__(1024) void k_scan(const int* __restrict__ counts, int* __restrict__ offs, int n) {
  __shared__ int buf[1024];
  __shared__ int carry;
  if (threadIdx.x == 0) carry = 0;
  __syncthreads();
  for (int base = 0; base < n; base += 1024) {
    int i = base + threadIdx.x;
    int v = (i < n) ? counts[i] : 0;
    buf[threadIdx.x] = v;
    __syncthreads();
#pragma unroll
    for (int s = 1; s < 1024; s <<= 1) {
      int t = (threadIdx.x >= s) ? buf[threadIdx.x - s] : 0;
      __syncthreads();
      buf[threadIdx.x] += t;
      __syncthreads();
    }
    if (i < n) offs[i] = carry + buf[threadIdx.x] - v;  // exclusive
    __syncthreads();
    if (threadIdx.x == 0) carry += buf[1023];
    __syncthreads();
  }
  if (threadIdx.x == 0) offs[n] = carry;
}

// ---------- scatter edges into CSR-by-dst (src + precomputed norm) ----------
__global__ void k_scatter(const int* __restrict__ ei, const float* __restrict__ ew,
                          const float* __restrict__ dinv, const int* __restrict__ offs,
                          int* __restrict__ cursor, int* __restrict__ srcs,
                          float* __restrict__ norms, int E) {
  int e = blockIdx.x * 256 + threadIdx.x;
  if (e >= E) return;
  int s = ei[e], d = ei[E + e];
  int pos = offs[d] + atomicAdd(&cursor[d], 1);
  srcs[pos] = s;
  norms[pos] = dinv[s] * ew[e] * dinv[d];
}

// ---------- x -> bf16 ----------
__global__ void k_xbf(const float* __restrict__ x, bf16* __restrict__ xbf, int n8) {
  int i = blockIdx.x * 256 + threadIdx.x;
  if (i >= n8) return;
  const f4* x4 = (const f4*)x;
  f4 a = x4[2 * i], b = x4[2 * i + 1];
  bf8v o;
#pragma unroll
  for (int j = 0; j < 4; ++j) { o[j] = (bf16)a[j]; o[4 + j] = (bf16)b[j]; }
  ((bf8v*)xbf)[i] = o;
}

// ---------- gather-aggregate: one wave per dst node, f32 reg accum, write ybf ----------
__global__ __launch_bounds__(256) void k_agg(const int* __restrict__ offs, const int* __restrict__ srcs,
                                             const float* __restrict__ norms, const float* __restrict__ x,
                                             const float* __restrict__ dinv, const bf16* __restrict__ xbf,
                                             bf16* __restrict__ ybf) {
  int wv = (blockIdx.x * 256 + threadIdx.x) >> 6;
  int lane = threadIdx.x & 63;
  if (wv >= MPAD) return;
  bf16* yrow = ybf + ((size_t)wv << 9) + lane * 8;
  if (wv >= NN) {
    bf8v z;
#pragma unroll
    for (int j = 0; j < 8; ++j) z[j] = (bf16)0.f;
    *(bf8v*)yrow = z;
    return;
  }
  float acc[8];
  float s0 = dinv[wv]; s0 *= s0;
  const f4* xr = (const f4*)(x + ((size_t)wv << 9)) + lane * 2;
  f4 a = xr[0], b = xr[1];
#pragma unroll
  for (int j = 0; j < 4; ++j) { acc[j] = s0 * a[j]; acc[4 + j] = s0 * b[j]; }
  int e = offs[wv], end = offs[wv + 1];
  for (; e + 2 <= end; e += 2) {
    int s1 = srcs[e], s2 = srcs[e + 1];
    float n1 = norms[e], n2 = norms[e + 1];
    bf8v v1 = *(const bf8v*)(xbf + ((size_t)s1 << 9) + lane * 8);
    bf8v v2 = *(const bf8v*)(xbf + ((size_t)s2 << 9) + lane * 8);
#pragma unroll
    for (int j = 0; j < 8; ++j) acc[j] += n1 * (float)v1[j] + n2 * (float)v2[j];
  }
  if (e < end) {
    int s1 = srcs[e]; float n1 = norms[e];
    bf8v v1 = *(const bf8v*)(xbf + ((size_t)s1 << 9) + lane * 8);
#pragma unroll
    for (int j = 0; j < 8; ++j) acc[j] += n1 * (float)v1[j];
  }
  bf8v o;
#pragma unroll
  for (int j = 0; j < 8; ++j) o[j] = (bf16)acc[j];
  *(bf8v*)yrow = o;
}

// ---------- W_comb precompute: Wt[g][j][k] = sum_c Wc_g[k][c] * Wl_g[c][j] (bf16, transposed) ----------
__global__ void k_wcomb(const float* __restrict__ WcA, const float* __restrict__ WlA,
                        const float* __restrict__ WcB, const float* __restrict__ WlB,
                        const float* __restrict__ WcC, const float* __restrict__ WlC,
                        bf16* __restrict__ Wt) {
  const float* Wc; const float* Wl;
  int g = blockIdx.z;
  if (g == 0)      { Wc = WcA; Wl = WlA; }
  else if (g == 1) { Wc = WcB; Wl = WlB; }
  else             { Wc = WcC; Wl = WlC; }
  int k0 = blockIdx.x * 64, j0 = blockIdx.y * 64;
  int t = threadIdx.x, tx = t & 15, ty = t >> 4;
  __shared__ float sWc[64][17];  // [k][c]
  __shared__ float sWl[16][64];  // [c][j]
  float acc[4][4] = {};
  for (int c0 = 0; c0 < 512; c0 += 16) {
    { int kk = t >> 2, c4 = (t & 3) * 4;
      f4 v = *(const f4*)(Wc + (size_t)(k0 + kk) * 512 + c0 + c4);
#pragma unroll
      for (int j = 0; j < 4; ++j) sWc[kk][c4 + j] = v[j]; }
    { int cc = t >> 4, j4 = (t & 15) * 4;
      f4 v = *(const f4*)(Wl + (size_t)(c0 + cc) * 512 + j0 + j4);
      *(f4*)&sWl[cc][j4] = v; }
    __syncthreads();
#pragma unroll
    for (int cc = 0; cc < 16; ++cc) {
      float wcv[4], wlv[4];
#pragma unroll
      for (int b = 0; b < 4; ++b) wcv[b] = sWc[tx * 4 + b][cc];
#pragma unroll
      for (int a = 0; a < 4; ++a) wlv[a] = sWl[cc][ty * 4 + a];
#pragma unroll
      for (int a = 0; a < 4; ++a)
#pragma unroll
        for (int b = 0; b < 4; ++b) acc[a][b] += wlv[a] * wcv[b];
    }
    __syncthreads();
  }
#pragma unroll
  for (int a = 0; a < 4; ++a) {
    bf4v o;
#pragma unroll
    for (int b = 0; b < 4; ++b) o[b] = (bf16)acc[a][b];
    *(bf4v*)&Wt[((size_t)g * 512 + j0 + ty * 4 + a) * 512 + k0 + tx * 4] = o;
  }
}

// ---------- combined bias: bcomb[g][j] = bl_g[j] + sum_c bc_g[c]*Wl_g[c][j] ----------
__global__ void k_bcomb2(const float* __restrict__ bcA, const float* __restrict__ blA, const float* __restrict__ WlA,
                         const float* __restrict__ bcB, const float* __restrict__ blB, const float* __restrict__ WlB,
                         const float* __restrict__ bcC, const float* __restrict__ blC, const float* __restrict__ WlC,
                         float* __restrict__ bcomb) {
  int t = blockIdx.x * 256 + threadIdx.x;
  if (t >= 1536) return;
  int g = t >> 9, j = t & 511;
  const float* bc; const float* bl; const float* Wl;
  if (g == 0)      { bc = bcA; bl = blA; Wl = WlA; }
  else if (g == 1) { bc = bcB; bl = blB; Wl = WlB; }
  else             { bc = bcC; bl = blC; Wl = WlC; }
  float s = bl[j];
  for (int c = 0; c < 512; ++c) s += bc[c] * Wl[(size_t)c * 512 + j];
  bcomb[t] = s;
}

// ---------- main fused GEMM: Z = ybf @ Wt^T per gate, epilogue -> O/Hn/Cn ----------
__global__ __launch_bounds__(256) void k_gemm(const bf16* __restrict__ A, const bf16* __restrict__ Bt,
                                              const float* __restrict__ bcomb, float* __restrict__ out) {
  __shared__ __align__(16) char lds[40960];  // A: [0,16384) B: 3 x 8192
  const int t = threadIdx.x, lane = t & 63, w = t >> 6;
  const int wm = w >> 1, wn = w & 1;
  const int m0 = blockIdx.y * 128, n0 = blockIdx.x * 64;
  const int l15 = lane & 15, lhi = lane >> 4;
  f32x4 acc[3][4][2] = {};

  for (int ks = 0; ks < 8; ++ks) {
    const int k0 = ks * 64;
    // stage A tile 128x64 bf16 (16KB), linear dest + pre-swizzled source
#pragma unroll
    for (int it = 0; it < 4; ++it) {
      int P = (((it * 4 + w) << 6) | lane) << 4;  // physical byte in A tile
      int r = P >> 7;
      int wl = (P & 127) ^ ((r & 7) << 4);
      const char* src = (const char*)A + (((size_t)(m0 + r)) << 10) + (k0 << 1) + wl;
      gl_lds16(src, lds + P);
    }
    // stage B tiles: 3 gates x 64x64 bf16 (8KB each), rows are n, cols k
#pragma unroll
    for (int it = 0; it < 6; ++it) {
      int flat = it * 4 + w;          // 0..23
      int g = flat >> 3, q = flat & 7;
      int P = ((q << 6) | lane) << 4; // byte within gate tile
      int n = P >> 7;
      int wl = (P & 127) ^ ((n & 7) << 4);
      const char* src = (const char*)Bt + (((size_t)(g * 512 + n0 + n)) << 10) + (k0 << 1) + wl;
      gl_lds16(src, lds + 16384 + g * 8192 + P);
    }
    asm volatile("s_waitcnt vmcnt(0)" ::: "memory");
    __syncthreads();
#pragma unroll
    for (int kh = 0; kh < 2; ++kh) {
      bf8v af[4];
#pragma unroll
      for (int mi = 0; mi < 4; ++mi) {
        int r = wm * 64 + mi * 16 + l15;
        int off = (kh * 64 + lhi * 16) ^ ((r & 7) << 4);
        af[mi] = *(const bf8v*)(lds + r * 128 + off);
      }
      bf8v bfr[3][2];
#pragma unroll
      for (int g = 0; g < 3; ++g)
#pragma unroll
        for (int ni = 0; ni < 2; ++ni) {
          int n = wn * 32 + ni * 16 + l15;
          int off = (kh * 64 + lhi * 16) ^ ((n & 7) << 4);
          bfr[g][ni] = *(const bf8v*)(lds + 16384 + g * 8192 + n * 128 + off);
        }
#pragma unroll
      for (int g = 0; g < 3; ++g)
#pragma unroll
        for (int mi = 0; mi < 4; ++mi)
#pragma unroll
          for (int ni = 0; ni < 2; ++ni)
            acc[g][mi][ni] = __builtin_amdgcn_mfma_f32_16x16x32_bf16(af[mi], bfr[g][ni], acc[g][mi][ni], 0, 0, 0);
    }
    __syncthreads();
  }

  // epilogue: gates + LSTM combine, write O/Hn/Cn
#pragma unroll
  for (int ni = 0; ni < 2; ++ni) {
    int col = n0 + wn * 32 + ni * 16 + l15;
    float bI = bcomb[col], bG = bcomb[512 + col], bO = bcomb[1024 + col];
#pragma unroll
    for (int mi = 0; mi < 4; ++mi) {
#pragma unroll
      for (int r = 0; r < 4; ++r) {
        int row = m0 + wm * 64 + mi * 16 + lhi * 4 + r;
        if (row < NN) {
          float zi = acc[0][mi][ni][r] + bI;
          float zg = acc[1][mi][ni][r] + bG;
          float zo = acc[2][mi][ni][r] + bO;
          float I = 1.f / (1.f + __expf(-zi));
          float e2g = __expf(2.f * zg);
          float G = (e2g - 1.f) / (e2g + 1.f);
          float O = 1.f / (1.f + __expf(-zo));
          float Cn = I * G;
          float e2c = __expf(2.f * Cn);
          float tc = (e2c - 1.f) / (e2c + 1.f);
          float Hn = O * tc;
          size_t base = ((size_t)row << 9) + col;
          out[base] = O;
          out[OUTSTRIDE + base] = Hn;
          out[2 * OUTSTRIDE + base] = Cn;
        }
      }
    }
  }
}

extern "C" void kernel_launch(void* const* d_in, const int* in_sizes, int n_in,
                              void* d_out, int out_size, void* d_ws, size_t ws_size,
                              hipStream_t stream) {
  const float* x   = (const float*)d_in[0];
  const int*   ei  = (const int*)d_in[1];
  const float* ew  = (const float*)d_in[2];
  const float* Wc_i = (const float*)d_in[3];
  const float* bc_i = (const float*)d_in[4];
  const float* Wl_i = (const float*)d_in[5];
  const float* bl_i = (const float*)d_in[6];
  // F gate (d_in[7..10]) is dead: Cn = F*0 + I*G
  const float* Wc_g = (const float*)d_in[11];
  const float* bc_g = (const float*)d_in[12];
  const float* Wl_g = (const float*)d_in[13];
  const float* bl_g = (const float*)d_in[14];
  const float* Wc_o = (const float*)d_in[15];
  const float* bc_o = (const float*)d_in[16];
  const float* Wl_o = (const float*)d_in[17];
  const float* bl_o = (const float*)d_in[18];

  const int E = in_sizes[2];
  const int n = in_sizes[0] / 512;  // 30000

  // workspace layout (known-working 32.5MB footprint)
  char* ws = (char*)d_ws;
  bf16*  ybf   = (bf16*)ws;                      // MPAD*512*2  = 30,801,920
  float* dinv  = (float*)(ws + 30801920);        // 120,000
  bf16*  Wt    = (bf16*)(ws + 30924800);         // 3*512*512*2 = 1,572,864
  float* bcomb = (float*)(ws + 32497664);        // 6,144
  (void)ws_size;

  // scratch inside d_out (184.3MB; all dead before k_gemm's epilogue writes)
  char* ob = (char*)d_out;
  float* out   = (float*)d_out;
  bf16*  xbf   = (bf16*)ob;                  // [0, 30,720,000)
  int*   srcs  = (int*)(ob + 30720000);      // 1,920,000
  float* norms = (float*)(ob + 32640000);    // 1,920,000
  int*   cnts  = (int*)(ob + 34560000);      // 120,000
  int*   offs  = (int*)(ob + 34680000);      // 120,016 (n+1 ints)
  int*   curs  = (int*)(ob + 34800016);      // 120,000
  (void)out_size; (void)n_in;

  k_init<<<(n + 255) / 256, 256, 0, stream>>>(dinv, cnts, curs, n);
  k_pre<<<(E + 255) / 256, 256, 0, stream>>>(ei, ew, dinv, cnts, E);
  k_dinv<<<(n + 255) / 256, 256, 0, stream>>>(dinv, n);
  k_scan<<<1, 1024, 0, stream>>>(cnts, offs, n);
  k_scatter<<<(E + 255) / 256, 256, 0, stream>>>(ei, ew, dinv, offs, curs, srcs, norms, E);
  k_xbf<<<(n * 512 / 8 + 255) / 256, 256, 0, stream>>>(x, xbf, n * 512 / 8);
  k_agg<<<(MPAD * 64 + 255) / 256, 256, 0, stream>>>(offs, srcs, norms, x, dinv, xbf, ybf);
  k_wcomb<<<dim3(8, 8, 3), 256, 0, stream>>>(Wc_i, Wl_i, Wc_g, Wl_g, Wc_o, Wl_o, Wt);
  k_bcomb2<<<6, 256, 0, stream>>>(bc_i, bl_i, Wl_i, bc_g, bl_g, Wl_g, bc_o, bl_o, Wl_o, bcomb);
  k_gemm<<<dim3(8, 235), 256, 0, stream>>>(ybf, Wt, bcomb, out);
}

// Round 3
// 327.106 us; speedup vs baseline: 20.6716x; 1.2010x over previous
//
#include <hip/hip_runtime.h>
#include <stdint.h>

typedef __bf16 bf16;
typedef __attribute__((ext_vector_type(4))) float f4;
typedef __attribute__((ext_vector_type(4))) float f32x4;
typedef __attribute__((ext_vector_type(8))) __bf16 bf8v;
typedef __attribute__((ext_vector_type(4))) __bf16 bf4v;

#define NN 30000
#define MPAD 30080
#define OUTSTRIDE 15360000  // 30000*512

typedef __attribute__((address_space(3))) unsigned int as3_u32;
typedef __attribute__((address_space(1))) unsigned int as1_u32;

__device__ __forceinline__ void gl_lds16(const void* g, void* l) {
  __builtin_amdgcn_global_load_lds((as1_u32*)g, (as3_u32*)l, 16, 0, 0);
}

// ---------- init: deg=1 (self loop), counts=0, cursor=0 ----------
__global__ void k_init(float* deg, int* counts, int* cursor, int n) {
  int i = blockIdx.x * 256 + threadIdx.x;
  if (i < n) { deg[i] = 1.0f; counts[i] = 0; cursor[i] = 0; }
}

// ---------- per-edge: degree accum + dst histogram ----------
__global__ void k_pre(const int* __restrict__ ei, const float* __restrict__ ew,
                      float* __restrict__ deg, int* __restrict__ counts, int E) {
  int e = blockIdx.x * 256 + threadIdx.x;
  if (e < E) {
    int d = ei[E + e];
    atomicAdd(&deg[d], ew[e]);
    atomicAdd(&counts[d], 1);
  }
}

__global__ void k_dinv(float* dinv, int n) {
  int i = blockIdx.x * 256 + threadIdx.x;
  if (i < n) { float d = dinv[i]; dinv[i] = d > 0.f ? rsqrtf(d) : 0.f; }
}

// ---------- hierarchical exclusive scan: bsum -> bscan -> offs ----------
__global__ void k_bsum(const int* __restrict__ counts, int* __restrict__ bsum, int n) {
  __shared__ int sm[256];
  int i = blockIdx.x * 256 + threadIdx.x;
  sm[threadIdx.x] = (i < n) ? counts[i] : 0;
  __syncthreads();
  for (int st = 128; st > 0; st >>= 1) {
    if (threadIdx.x < st) sm[threadIdx.x] += sm[threadIdx.x + st];
    __syncthreads();
  }
  if (threadIdx.x == 0) bsum[blockIdx.x] = sm[0];
}

__global__ void k_bscan(int* bsum, int nb) {  // single block, 128 threads, nb <= 128
  __shared__ int buf[128];
  int t = threadIdx.x;
  int v = (t < nb) ? bsum[t] : 0;
  buf[t] = v;
  __syncthreads();
  for (int s = 1; s < 128; s <<= 1) {
    int u = (t >= s) ? buf[t - s] : 0;
    __syncthreads();
    buf[t] += u;
    __syncthreads();
  }
  if (t < nb) bsum[t] = buf[t] - v;  // exclusive
}

__global__ void k_offs(const int* __restrict__ counts, const int* __restrict__ bsum,
                       int* __restrict__ offs, int n, int E) {
  __shared__ int buf[256];
  int i = blockIdx.x * 256 + threadIdx.x;
  int v = (i < n) ? counts[i] : 0;
  buf[threadIdx.x] = v;
  __syncthreads();
  for (int s = 1; s < 256; s <<= 1) {
    int u = (threadIdx.x >= s) ? buf[threadIdx.x - s] : 0;
    __syncthreads();
    buf[threadIdx.x] += u;
    __syncthreads();
  }
  if (i < n) offs[i] = bsum[blockIdx.x] + buf[threadIdx.x] - v;
  if (i == 0) offs[n] = E;
}

// ---------- scatter edges into CSR-by-dst (src + precomputed norm) ----------
__global__ void k_scatter(const int* __restrict__ ei, const float* __restrict__ ew,
                          const float* __restrict__ dinv, const int* __restrict__ offs,
                          int* __restrict__ cursor, int* __restrict__ srcs,
                          float* __restrict__ norms, int E) {
  int e = blockIdx.x * 256 + threadIdx.x;
  if (e >= E) return;
  int s = ei[e], d = ei[E + e];
  int pos = offs[d] + atomicAdd(&cursor[d], 1);
  srcs[pos] = s;
  norms[pos] = dinv[s] * ew[e] * dinv[d];
}

// ---------- x -> bf16 ----------
__global__ void k_xbf(const float* __restrict__ x, bf16* __restrict__ xbf, int n8) {
  int i = blockIdx.x * 256 + threadIdx.x;
  if (i >= n8) return;
  const f4* x4 = (const f4*)x;
  f4 a = x4[2 * i], b = x4[2 * i + 1];
  bf8v o;
#pragma unroll
  for (int j = 0; j < 4; ++j) { o[j] = (bf16)a[j]; o[4 + j] = (bf16)b[j]; }
  ((bf8v*)xbf)[i] = o;
}

// ---------- gather-aggregate: one wave per dst node, f32 reg accum, write ybf ----------
__global__ __launch_bounds__(256) void k_agg(const int* __restrict__ offs, const int* __restrict__ srcs,
                                             const float* __restrict__ norms, const float* __restrict__ x,
                                             const float* __restrict__ dinv, const bf16* __restrict__ xbf,
                                             bf16* __restrict__ ybf) {
  int wv = (blockIdx.x * 256 + threadIdx.x) >> 6;
  int lane = threadIdx.x & 63;
  if (wv >= MPAD) return;
  bf16* yrow = ybf + ((size_t)wv << 9) + lane * 8;
  if (wv >= NN) {
    bf8v z;
#pragma unroll
    for (int j = 0; j < 8; ++j) z[j] = (bf16)0.f;
    *(bf8v*)yrow = z;
    return;
  }
  float acc[8];
  float s0 = dinv[wv]; s0 *= s0;
  const f4* xr = (const f4*)(x + ((size_t)wv << 9)) + lane * 2;
  f4 a = xr[0], b = xr[1];
#pragma unroll
  for (int j = 0; j < 4; ++j) { acc[j] = s0 * a[j]; acc[4 + j] = s0 * b[j]; }
  int e = offs[wv], end = offs[wv + 1];
  for (; e + 2 <= end; e += 2) {
    int s1 = srcs[e], s2 = srcs[e + 1];
    float n1 = norms[e], n2 = norms[e + 1];
    bf8v v1 = *(const bf8v*)(xbf + ((size_t)s1 << 9) + lane * 8);
    bf8v v2 = *(const bf8v*)(xbf + ((size_t)s2 << 9) + lane * 8);
#pragma unroll
    for (int j = 0; j < 8; ++j) acc[j] += n1 * (float)v1[j] + n2 * (float)v2[j];
  }
  if (e < end) {
    int s1 = srcs[e]; float n1 = norms[e];
    bf8v v1 = *(const bf8v*)(xbf + ((size_t)s1 << 9) + lane * 8);
#pragma unroll
    for (int j = 0; j < 8; ++j) acc[j] += n1 * (float)v1[j];
  }
  bf8v o;
#pragma unroll
  for (int j = 0; j < 8; ++j) o[j] = (bf16)acc[j];
  *(bf8v*)yrow = o;
}

// ---------- W_comb precompute: Wt[g][j][k] = sum_c Wc_g[k][c] * Wl_g[c][j] (bf16, transposed) ----------
__global__ void k_wcomb(const float* __restrict__ WcA, const float* __restrict__ WlA,
                        const float* __restrict__ WcB, const float* __restrict__ WlB,
                        const float* __restrict__ WcC, const float* __restrict__ WlC,
                        bf16* __restrict__ Wt) {
  const float* Wc; const float* Wl;
  int g = blockIdx.z;
  if (g == 0)      { Wc = WcA; Wl = WlA; }
  else if (g == 1) { Wc = WcB; Wl = WlB; }
  else             { Wc = WcC; Wl = WlC; }
  int k0 = blockIdx.x * 64, j0 = blockIdx.y * 64;
  int t = threadIdx.x, tx = t & 15, ty = t >> 4;
  __shared__ float sWc[64][17];  // [k][c]
  __shared__ float sWl[16][64];  // [c][j]
  float acc[4][4] = {};
  for (int c0 = 0; c0 < 512; c0 += 16) {
    { int kk = t >> 2, c4 = (t & 3) * 4;
      f4 v = *(const f4*)(Wc + (size_t)(k0 + kk) * 512 + c0 + c4);
#pragma unroll
      for (int j = 0; j < 4; ++j) sWc[kk][c4 + j] = v[j]; }
    { int cc = t >> 4, j4 = (t & 15) * 4;
      f4 v = *(const f4*)(Wl + (size_t)(c0 + cc) * 512 + j0 + j4);
      *(f4*)&sWl[cc][j4] = v; }
    __syncthreads();
#pragma unroll
    for (int cc = 0; cc < 16; ++cc) {
      float wcv[4], wlv[4];
#pragma unroll
      for (int b = 0; b < 4; ++b) wcv[b] = sWc[tx * 4 + b][cc];
#pragma unroll
      for (int a = 0; a < 4; ++a) wlv[a] = sWl[cc][ty * 4 + a];
#pragma unroll
      for (int a = 0; a < 4; ++a)
#pragma unroll
        for (int b = 0; b < 4; ++b) acc[a][b] += wlv[a] * wcv[b];
    }
    __syncthreads();
  }
#pragma unroll
  for (int a = 0; a < 4; ++a) {
    bf4v o;
#pragma unroll
    for (int b = 0; b < 4; ++b) o[b] = (bf16)acc[a][b];
    *(bf4v*)&Wt[((size_t)g * 512 + j0 + ty * 4 + a) * 512 + k0 + tx * 4] = o;
  }
}

// ---------- combined bias: bcomb[g][j] = bl_g[j] + sum_c bc_g[c]*Wl_g[c][j] ----------
__global__ void k_bcomb3(const float* __restrict__ bcA, const float* __restrict__ blA, const float* __restrict__ WlA,
                         const float* __restrict__ bcB, const float* __restrict__ blB, const float* __restrict__ WlB,
                         const float* __restrict__ bcC, const float* __restrict__ blC, const float* __restrict__ WlC,
                         float* __restrict__ bcomb) {
  int g = blockIdx.x >> 3, jc = blockIdx.x & 7;
  const float* bc; const float* bl; const float* Wl;
  if (g == 0)      { bc = bcA; bl = blA; Wl = WlA; }
  else if (g == 1) { bc = bcB; bl = blB; Wl = WlB; }
  else             { bc = bcC; bl = blC; Wl = WlC; }
  int jl = threadIdx.x & 63, part = threadIdx.x >> 6;
  int j = jc * 64 + jl;
  float s = 0.f;
  for (int c = part * 128; c < part * 128 + 128; ++c)
    s += bc[c] * Wl[(size_t)c * 512 + j];
  __shared__ float sm[4][64];
  sm[part][jl] = s;
  __syncthreads();
  if (part == 0)
    bcomb[g * 512 + j] = bl[j] + sm[0][jl] + sm[1][jl] + sm[2][jl] + sm[3][jl];
}

// ---------- main fused GEMM: Z = ybf @ Wt^T per gate, epilogue -> O/Hn/Cn ----------
// Double-buffered 2-phase schedule + XCD-aware swizzle (1880 = 8*235 blocks).
__global__ __launch_bounds__(256) void k_gemm(const bf16* __restrict__ A, const bf16* __restrict__ Bt,
                                              const float* __restrict__ bcomb, float* __restrict__ out) {
  __shared__ __align__(16) char lds[81920];  // 2 buffers x (A 16KB + B 3x8KB)
  const int t = threadIdx.x, lane = t & 63, w = t >> 6;
  const int wm = w >> 1, wn = w & 1;
  // XCD swizzle: all 8 n-blocks of one m-row land on the same XCD (d%8).
  const int d = blockIdx.x;
  const int s = (d & 7) * 235 + (d >> 3);
  const int m0 = (s >> 3) * 128, n0 = (s & 7) * 64;
  const int l15 = lane & 15, lhi = lane >> 4;
  f32x4 acc[3][4][2] = {};

  auto stage = [&](char* base, int ks) {
    const int k0b = ks * 128;  // byte offset within a 1KB row
#pragma unroll
    for (int it = 0; it < 4; ++it) {
      int P = (((it * 4 + w) << 6) | lane) << 4;  // physical byte in A tile
      int r = P >> 7;
      int wl = (P & 127) ^ ((r & 7) << 4);
      gl_lds16((const char*)A + (((size_t)(m0 + r)) << 10) + k0b + wl, base + P);
    }
#pragma unroll
    for (int it = 0; it < 6; ++it) {
      int flat = it * 4 + w;          // 0..23
      int g = flat >> 3, q = flat & 7;
      int P = ((q << 6) | lane) << 4; // byte within gate tile
      int n = P >> 7;
      int wl = (P & 127) ^ ((n & 7) << 4);
      gl_lds16((const char*)Bt + (((size_t)(g * 512 + n0 + n)) << 10) + k0b + wl,
               base + 16384 + g * 8192 + P);
    }
  };

  auto compute = [&](const char* base) {
#pragma unroll
    for (int kh = 0; kh < 2; ++kh) {
      bf8v af[4];
#pragma unroll
      for (int mi = 0; mi < 4; ++mi) {
        int r = wm * 64 + mi * 16 + l15;
        int off = (kh * 64 + lhi * 16) ^ ((r & 7) << 4);
        af[mi] = *(const bf8v*)(base + r * 128 + off);
      }
      bf8v bfr[3][2];
#pragma unroll
      for (int g = 0; g < 3; ++g)
#pragma unroll
        for (int ni = 0; ni < 2; ++ni) {
          int n = wn * 32 + ni * 16 + l15;
          int off = (kh * 64 + lhi * 16) ^ ((n & 7) << 4);
          bfr[g][ni] = *(const bf8v*)(base + 16384 + g * 8192 + n * 128 + off);
        }
#pragma unroll
      for (int g = 0; g < 3; ++g)
#pragma unroll
        for (int mi = 0; mi < 4; ++mi)
#pragma unroll
          for (int ni = 0; ni < 2; ++ni)
            acc[g][mi][ni] = __builtin_amdgcn_mfma_f32_16x16x32_bf16(af[mi], bfr[g][ni], acc[g][mi][ni], 0, 0, 0);
    }
  };

  // prologue
  stage(lds, 0);
  __syncthreads();  // drains vmcnt(0)
#pragma unroll
  for (int kp = 0; kp < 4; ++kp) {
    stage(lds + 40960, 2 * kp + 1);   // issue next-tile loads first (overlap with MFMA)
    compute(lds);
    __syncthreads();                  // next buffer staged; everyone done with cur
    if (kp < 3) stage(lds, 2 * kp + 2);
    compute(lds + 40960);
    __syncthreads();
  }

  // epilogue: gates + LSTM combine, write O/Hn/Cn
#pragma unroll
  for (int ni = 0; ni < 2; ++ni) {
    int col = n0 + wn * 32 + ni * 16 + l15;
    float bI = bcomb[col], bG = bcomb[512 + col], bO = bcomb[1024 + col];
#pragma unroll
    for (int mi = 0; mi < 4; ++mi) {
#pragma unroll
      for (int r = 0; r < 4; ++r) {
        int row = m0 + wm * 64 + mi * 16 + lhi * 4 + r;
        if (row < NN) {
          float zi = acc[0][mi][ni][r] + bI;
          float zg = acc[1][mi][ni][r] + bG;
          float zo = acc[2][mi][ni][r] + bO;
          float I = 1.f / (1.f + __expf(-zi));
          float e2g = __expf(2.f * zg);
          float G = (e2g - 1.f) / (e2g + 1.f);
          float O = 1.f / (1.f + __expf(-zo));
          float Cn = I * G;
          float e2c = __expf(2.f * Cn);
          float tc = (e2c - 1.f) / (e2c + 1.f);
          float Hn = O * tc;
          size_t base = ((size_t)row << 9) + col;
          out[base] = O;
          out[OUTSTRIDE + base] = Hn;
          out[2 * OUTSTRIDE + base] = Cn;
        }
      }
    }
  }
}

extern "C" void kernel_launch(void* const* d_in, const int* in_sizes, int n_in,
                              void* d_out, int out_size, void* d_ws, size_t ws_size,
                              hipStream_t stream) {
  const float* x   = (const float*)d_in[0];
  const int*   ei  = (const int*)d_in[1];
  const float* ew  = (const float*)d_in[2];
  const float* Wc_i = (const float*)d_in[3];
  const float* bc_i = (const float*)d_in[4];
  const float* Wl_i = (const float*)d_in[5];
  const float* bl_i = (const float*)d_in[6];
  // F gate (d_in[7..10]) is dead: Cn = F*0 + I*G
  const float* Wc_g = (const float*)d_in[11];
  const float* bc_g = (const float*)d_in[12];
  const float* Wl_g = (const float*)d_in[13];
  const float* bl_g = (const float*)d_in[14];
  const float* Wc_o = (const float*)d_in[15];
  const float* bc_o = (const float*)d_in[16];
  const float* Wl_o = (const float*)d_in[17];
  const float* bl_o = (const float*)d_in[18];

  const int E = in_sizes[2];
  const int n = in_sizes[0] / 512;  // 30000
  const int NB = (n + 255) / 256;   // 118

  // workspace layout
  char* ws = (char*)d_ws;
  bf16*  ybf   = (bf16*)ws;                      // MPAD*512*2  = 30,801,920
  float* dinv  = (float*)(ws + 30801920);        // 120,000
  bf16*  Wt    = (bf16*)(ws + 30924800);         // 3*512*512*2 = 1,572,864
  float* bcomb = (float*)(ws + 32497664);        // 6,144
  int*   bsum  = (int*)(ws + 32503808);          // 512
  (void)ws_size;

  // scratch inside d_out (184.3MB; all dead before k_gemm's epilogue writes)
  char* ob = (char*)d_out;
  float* out   = (float*)d_out;
  bf16*  xbf   = (bf16*)ob;                  // [0, 30,720,000)
  int*   srcs  = (int*)(ob + 30720000);      // 1,920,000
  float* norms = (float*)(ob + 32640000);    // 1,920,000
  int*   cnts  = (int*)(ob + 34560000);      // 120,000
  int*   offs  = (int*)(ob + 34680000);      // 120,016 (n+1 ints)
  int*   curs  = (int*)(ob + 34800016);      // 120,000
  (void)out_size; (void)n_in;

  k_init<<<NB, 256, 0, stream>>>(dinv, cnts, curs, n);
  k_pre<<<(E + 255) / 256, 256, 0, stream>>>(ei, ew, dinv, cnts, E);
  k_dinv<<<NB, 256, 0, stream>>>(dinv, n);
  k_bsum<<<NB, 256, 0, stream>>>(cnts, bsum, n);
  k_bscan<<<1, 128, 0, stream>>>(bsum, NB);
  k_offs<<<NB, 256, 0, stream>>>(cnts, bsum, offs, n, E);
  k_scatter<<<(E + 255) / 256, 256, 0, stream>>>(ei, ew, dinv, offs, curs, srcs, norms, E);
  k_xbf<<<(n * 512 / 8 + 255) / 256, 256, 0, stream>>>(x, xbf, n * 512 / 8);
  k_agg<<<(MPAD * 64 + 255) / 256, 256, 0, stream>>>(offs, srcs, norms, x, dinv, xbf, ybf);
  k_wcomb<<<dim3(8, 8, 3), 256, 0, stream>>>(Wc_i, Wl_i, Wc_g, Wl_g, Wc_o, Wl_o, Wt);
  k_bcomb3<<<24, 256, 0, stream>>>(bc_i, bl_i, Wl_i, bc_g, bl_g, Wl_g, bc_o, bl_o, Wl_o, bcomb);
  k_gemm<<<1880, 256, 0, stream>>>(ybf, Wt, bcomb, out);
}

// Round 4
// 326.800 us; speedup vs baseline: 20.6910x; 1.0009x over previous
//
#include <hip/hip_runtime.h>
#include <stdint.h>

typedef __bf16 bf16;
typedef __attribute__((ext_vector_type(4))) float f4;
typedef __attribute__((ext_vector_type(4))) float f32x4;
typedef __attribute__((ext_vector_type(8))) __bf16 bf8v;
typedef __attribute__((ext_vector_type(4))) __bf16 bf4v;

#define NN 30000
#define MPAD 30080
#define OUTSTRIDE 15360000  // 30000*512

typedef __attribute__((address_space(3))) unsigned int as3_u32;
typedef __attribute__((address_space(1))) unsigned int as1_u32;

__device__ __forceinline__ void gl_lds16(const void* g, void* l) {
  __builtin_amdgcn_global_load_lds((as1_u32*)g, (as3_u32*)l, 16, 0, 0);
}

// ---------- init: deg=1 (self loop), counts=0, cursor=0 ----------
__global__ void k_init(float* deg, int* counts, int* cursor, int n) {
  int i = blockIdx.x * 256 + threadIdx.x;
  if (i < n) { deg[i] = 1.0f; counts[i] = 0; cursor[i] = 0; }
}

// ---------- per-edge: degree accum + dst histogram ----------
__global__ void k_pre(const int* __restrict__ ei, const float* __restrict__ ew,
                      float* __restrict__ deg, int* __restrict__ counts, int E) {
  int e = blockIdx.x * 256 + threadIdx.x;
  if (e < E) {
    int d = ei[E + e];
    atomicAdd(&deg[d], ew[e]);
    atomicAdd(&counts[d], 1);
  }
}

__global__ void k_dinv(float* dinv, int n) {
  int i = blockIdx.x * 256 + threadIdx.x;
  if (i < n) { float d = dinv[i]; dinv[i] = d > 0.f ? rsqrtf(d) : 0.f; }
}

// ---------- hierarchical exclusive scan: bsum -> bscan -> offs ----------
__global__ void k_bsum(const int* __restrict__ counts, int* __restrict__ bsum, int n) {
  __shared__ int sm[256];
  int i = blockIdx.x * 256 + threadIdx.x;
  sm[threadIdx.x] = (i < n) ? counts[i] : 0;
  __syncthreads();
  for (int st = 128; st > 0; st >>= 1) {
    if (threadIdx.x < st) sm[threadIdx.x] += sm[threadIdx.x + st];
    __syncthreads();
  }
  if (threadIdx.x == 0) bsum[blockIdx.x] = sm[0];
}

__global__ void k_bscan(int* bsum, int nb) {  // single block, 128 threads, nb <= 128
  __shared__ int buf[128];
  int t = threadIdx.x;
  int v = (t < nb) ? bsum[t] : 0;
  buf[t] = v;
  __syncthreads();
  for (int s = 1; s < 128; s <<= 1) {
    int u = (t >= s) ? buf[t - s] : 0;
    __syncthreads();
    buf[t] += u;
    __syncthreads();
  }
  if (t < nb) bsum[t] = buf[t] - v;  // exclusive
}

__global__ void k_offs(const int* __restrict__ counts, const int* __restrict__ bsum,
                       int* __restrict__ offs, int n, int E) {
  __shared__ int buf[256];
  int i = blockIdx.x * 256 + threadIdx.x;
  int v = (i < n) ? counts[i] : 0;
  buf[threadIdx.x] = v;
  __syncthreads();
  for (int s = 1; s < 256; s <<= 1) {
    int u = (threadIdx.x >= s) ? buf[threadIdx.x - s] : 0;
    __syncthreads();
    buf[threadIdx.x] += u;
    __syncthreads();
  }
  if (i < n) offs[i] = bsum[blockIdx.x] + buf[threadIdx.x] - v;
  if (i == 0) offs[n] = E;
}

// ---------- scatter edges into CSR-by-dst (src + precomputed norm) ----------
__global__ void k_scatter(const int* __restrict__ ei, const float* __restrict__ ew,
                          const float* __restrict__ dinv, const int* __restrict__ offs,
                          int* __restrict__ cursor, int* __restrict__ srcs,
                          float* __restrict__ norms, int E) {
  int e = blockIdx.x * 256 + threadIdx.x;
  if (e >= E) return;
  int s = ei[e], d = ei[E + e];
  int pos = offs[d] + atomicAdd(&cursor[d], 1);
  srcs[pos] = s;
  norms[pos] = dinv[s] * ew[e] * dinv[d];
}

// ---------- x -> bf16 ----------
__global__ void k_xbf(const float* __restrict__ x, bf16* __restrict__ xbf, int n8) {
  int i = blockIdx.x * 256 + threadIdx.x;
  if (i >= n8) return;
  const f4* x4 = (const f4*)x;
  f4 a = x4[2 * i], b = x4[2 * i + 1];
  bf8v o;
#pragma unroll
  for (int j = 0; j < 4; ++j) { o[j] = (bf16)a[j]; o[4 + j] = (bf16)b[j]; }
  ((bf8v*)xbf)[i] = o;
}

// ---------- gather-aggregate: one wave per dst node, f32 reg accum, write ybf ----------
__global__ __launch_bounds__(256) void k_agg(const int* __restrict__ offs, const int* __restrict__ srcs,
                                             const float* __restrict__ norms, const float* __restrict__ x,
                                             const float* __restrict__ dinv, const bf16* __restrict__ xbf,
                                             bf16* __restrict__ ybf) {
  int wv = (blockIdx.x * 256 + threadIdx.x) >> 6;
  int lane = threadIdx.x & 63;
  if (wv >= MPAD) return;
  bf16* yrow = ybf + ((size_t)wv << 9) + lane * 8;
  if (wv >= NN) {
    bf8v z;
#pragma unroll
    for (int j = 0; j < 8; ++j) z[j] = (bf16)0.f;
    *(bf8v*)yrow = z;
    return;
  }
  float acc[8];
  float s0 = dinv[wv]; s0 *= s0;
  const f4* xr = (const f4*)(x + ((size_t)wv << 9)) + lane * 2;
  f4 a = xr[0], b = xr[1];
#pragma unroll
  for (int j = 0; j < 4; ++j) { acc[j] = s0 * a[j]; acc[4 + j] = s0 * b[j]; }
  int e = offs[wv], end = offs[wv + 1];
  for (; e + 2 <= end; e += 2) {
    int s1 = srcs[e], s2 = srcs[e + 1];
    float n1 = norms[e], n2 = norms[e + 1];
    bf8v v1 = *(const bf8v*)(xbf + ((size_t)s1 << 9) + lane * 8);
    bf8v v2 = *(const bf8v*)(xbf + ((size_t)s2 << 9) + lane * 8);
#pragma unroll
    for (int j = 0; j < 8; ++j) acc[j] += n1 * (float)v1[j] + n2 * (float)v2[j];
  }
  if (e < end) {
    int s1 = srcs[e]; float n1 = norms[e];
    bf8v v1 = *(const bf8v*)(xbf + ((size_t)s1 << 9) + lane * 8);
#pragma unroll
    for (int j = 0; j < 8; ++j) acc[j] += n1 * (float)v1[j];
  }
  bf8v o;
#pragma unroll
  for (int j = 0; j < 8; ++j) o[j] = (bf16)acc[j];
  *(bf8v*)yrow = o;
}

// ---------- W_comb precompute: Wt[g][j][k] = sum_c Wc_g[k][c] * Wl_g[c][j] (bf16, transposed) ----------
__global__ void k_wcomb(const float* __restrict__ WcA, const float* __restrict__ WlA,
                        const float* __restrict__ WcB, const float* __restrict__ WlB,
                        const float* __restrict__ WcC, const float* __restrict__ WlC,
                        bf16* __restrict__ Wt) {
  const float* Wc; const float* Wl;
  int g = blockIdx.z;
  if (g == 0)      { Wc = WcA; Wl = WlA; }
  else if (g == 1) { Wc = WcB; Wl = WlB; }
  else             { Wc = WcC; Wl = WlC; }
  int k0 = blockIdx.x * 64, j0 = blockIdx.y * 64;
  int t = threadIdx.x, tx = t & 15, ty = t >> 4;
  __shared__ float sWc[64][17];  // [k][c]
  __shared__ float sWl[16][64];  // [c][j]
  float acc[4][4] = {};
  for (int c0 = 0; c0 < 512; c0 += 16) {
    { int kk = t >> 2, c4 = (t & 3) * 4;
      f4 v = *(const f4*)(Wc + (size_t)(k0 + kk) * 512 + c0 + c4);
#pragma unroll
      for (int j = 0; j < 4; ++j) sWc[kk][c4 + j] = v[j]; }
    { int cc = t >> 4, j4 = (t & 15) * 4;
      f4 v = *(const f4*)(Wl + (size_t)(c0 + cc) * 512 + j0 + j4);
      *(f4*)&sWl[cc][j4] = v; }
    __syncthreads();
#pragma unroll
    for (int cc = 0; cc < 16; ++cc) {
      float wcv[4], wlv[4];
#pragma unroll
      for (int b = 0; b < 4; ++b) wcv[b] = sWc[tx * 4 + b][cc];
#pragma unroll
      for (int a = 0; a < 4; ++a) wlv[a] = sWl[cc][ty * 4 + a];
#pragma unroll
      for (int a = 0; a < 4; ++a)
#pragma unroll
        for (int b = 0; b < 4; ++b) acc[a][b] += wlv[a] * wcv[b];
    }
    __syncthreads();
  }
#pragma unroll
  for (int a = 0; a < 4; ++a) {
    bf4v o;
#pragma unroll
    for (int b = 0; b < 4; ++b) o[b] = (bf16)acc[a][b];
    *(bf4v*)&Wt[((size_t)g * 512 + j0 + ty * 4 + a) * 512 + k0 + tx * 4] = o;
  }
}

// ---------- combined bias: bcomb[g][j] = bl_g[j] + sum_c bc_g[c]*Wl_g[c][j] ----------
__global__ void k_bcomb3(const float* __restrict__ bcA, const float* __restrict__ blA, const float* __restrict__ WlA,
                         const float* __restrict__ bcB, const float* __restrict__ blB, const float* __restrict__ WlB,
                         const float* __restrict__ bcC, const float* __restrict__ blC, const float* __restrict__ WlC,
                         float* __restrict__ bcomb) {
  int g = blockIdx.x >> 3, jc = blockIdx.x & 7;
  const float* bc; const float* bl; const float* Wl;
  if (g == 0)      { bc = bcA; bl = blA; Wl = WlA; }
  else if (g == 1) { bc = bcB; bl = blB; Wl = WlB; }
  else             { bc = bcC; bl = blC; Wl = WlC; }
  int jl = threadIdx.x & 63, part = threadIdx.x >> 6;
  int j = jc * 64 + jl;
  float s = 0.f;
  for (int c = part * 128; c < part * 128 + 128; ++c)
    s += bc[c] * Wl[(size_t)c * 512 + j];
  __shared__ float sm[4][64];
  sm[part][jl] = s;
  __syncthreads();
  if (part == 0)
    bcomb[g * 512 + j] = bl[j] + sm[0][jl] + sm[1][jl] + sm[2][jl] + sm[3][jl];
}

// ---------- main fused GEMM: Z = ybf @ Wt^T per gate, epilogue -> O/Hn/Cn ----------
// Double-buffered 2-phase schedule + XCD-aware swizzle (1880 = 8*235 blocks).
// MFMA operands SWAPPED (D[n][m]): lane's 4 acc regs = 4 consecutive n columns
// -> epilogue stores are dwordx4 (24 per thread instead of 96 scalar).
__global__ __launch_bounds__(256) void k_gemm(const bf16* __restrict__ A, const bf16* __restrict__ Bt,
                                              const float* __restrict__ bcomb, float* __restrict__ out) {
  __shared__ __align__(16) char lds[81920];  // 2 buffers x (A 16KB + B 3x8KB)
  const int t = threadIdx.x, lane = t & 63, w = t >> 6;
  const int wm = w >> 1, wn = w & 1;
  // XCD swizzle: all 8 n-blocks of one m-row land on the same XCD (d%8).
  const int d = blockIdx.x;
  const int s = (d & 7) * 235 + (d >> 3);
  const int m0 = (s >> 3) * 128, n0 = (s & 7) * 64;
  const int l15 = lane & 15, lhi = lane >> 4;
  f32x4 acc[3][4][2] = {};

  auto stage = [&](char* base, int ks) {
    const int k0b = ks * 128;  // byte offset within a 1KB row
#pragma unroll
    for (int it = 0; it < 4; ++it) {
      int P = (((it * 4 + w) << 6) | lane) << 4;  // physical byte in A tile
      int r = P >> 7;
      int wl = (P & 127) ^ ((r & 7) << 4);
      gl_lds16((const char*)A + (((size_t)(m0 + r)) << 10) + k0b + wl, base + P);
    }
#pragma unroll
    for (int it = 0; it < 6; ++it) {
      int flat = it * 4 + w;          // 0..23
      int g = flat >> 3, q = flat & 7;
      int P = ((q << 6) | lane) << 4; // byte within gate tile
      int n = P >> 7;
      int wl = (P & 127) ^ ((n & 7) << 4);
      gl_lds16((const char*)Bt + (((size_t)(g * 512 + n0 + n)) << 10) + k0b + wl,
               base + 16384 + g * 8192 + P);
    }
  };

  auto compute = [&](const char* base) {
#pragma unroll
    for (int kh = 0; kh < 2; ++kh) {
      bf8v af[4];
#pragma unroll
      for (int mi = 0; mi < 4; ++mi) {
        int r = wm * 64 + mi * 16 + l15;
        int off = (kh * 64 + lhi * 16) ^ ((r & 7) << 4);
        af[mi] = *(const bf8v*)(base + r * 128 + off);
      }
      bf8v bfr[3][2];
#pragma unroll
      for (int g = 0; g < 3; ++g)
#pragma unroll
        for (int ni = 0; ni < 2; ++ni) {
          int n = wn * 32 + ni * 16 + l15;
          int off = (kh * 64 + lhi * 16) ^ ((n & 7) << 4);
          bfr[g][ni] = *(const bf8v*)(base + 16384 + g * 8192 + n * 128 + off);
        }
#pragma unroll
      for (int g = 0; g < 3; ++g)
#pragma unroll
        for (int mi = 0; mi < 4; ++mi)
#pragma unroll
          for (int ni = 0; ni < 2; ++ni)
            acc[g][mi][ni] = __builtin_amdgcn_mfma_f32_16x16x32_bf16(bfr[g][ni], af[mi], acc[g][mi][ni], 0, 0, 0);
    }
  };

  // prologue
  stage(lds, 0);
  __syncthreads();  // drains vmcnt(0)
#pragma unroll
  for (int kp = 0; kp < 4; ++kp) {
    stage(lds + 40960, 2 * kp + 1);   // issue next-tile loads first (overlap with MFMA)
    compute(lds);
    __syncthreads();                  // next buffer staged; everyone done with cur
    if (kp < 3) stage(lds, 2 * kp + 2);
    compute(lds + 40960);
    __syncthreads();
  }

  // epilogue: gates + LSTM combine, vectorized dwordx4 stores.
  // D[n][m]: m = ...+l15 (fixed per lane), n = ...+lhi*4+r (4 consecutive cols).
#pragma unroll
  for (int ni = 0; ni < 2; ++ni) {
    int nb = n0 + wn * 32 + ni * 16 + lhi * 4;
    f4 bI = *(const f4*)&bcomb[nb];
    f4 bG = *(const f4*)&bcomb[512 + nb];
    f4 bO = *(const f4*)&bcomb[1024 + nb];
#pragma unroll
    for (int mi = 0; mi < 4; ++mi) {
      int row = m0 + wm * 64 + mi * 16 + l15;
      if (row < NN) {
        f4 vO, vH, vC;
#pragma unroll
        for (int r = 0; r < 4; ++r) {
          float zi = acc[0][mi][ni][r] + bI[r];
          float zg = acc[1][mi][ni][r] + bG[r];
          float zo = acc[2][mi][ni][r] + bO[r];
          float I = 1.f / (1.f + __expf(-zi));
          float e2g = __expf(2.f * zg);
          float G = (e2g - 1.f) / (e2g + 1.f);
          float O = 1.f / (1.f + __expf(-zo));
          float Cn = I * G;
          float e2c = __expf(2.f * Cn);
          float tc = (e2c - 1.f) / (e2c + 1.f);
          vO[r] = O; vH[r] = O * tc; vC[r] = Cn;
        }
        size_t base = ((size_t)row << 9) + nb;
        *(f4*)&out[base] = vO;
        *(f4*)&out[OUTSTRIDE + base] = vH;
        *(f4*)&out[2 * OUTSTRIDE + base] = vC;
      }
    }
  }
}

extern "C" void kernel_launch(void* const* d_in, const int* in_sizes, int n_in,
                              void* d_out, int out_size, void* d_ws, size_t ws_size,
                              hipStream_t stream) {
  const float* x   = (const float*)d_in[0];
  const int*   ei  = (const int*)d_in[1];
  const float* ew  = (const float*)d_in[2];
  const float* Wc_i = (const float*)d_in[3];
  const float* bc_i = (const float*)d_in[4];
  const float* Wl_i = (const float*)d_in[5];
  const float* bl_i = (const float*)d_in[6];
  // F gate (d_in[7..10]) is dead: Cn = F*0 + I*G
  const float* Wc_g = (const float*)d_in[11];
  const float* bc_g = (const float*)d_in[12];
  const float* Wl_g = (const float*)d_in[13];
  const float* bl_g = (const float*)d_in[14];
  const float* Wc_o = (const float*)d_in[15];
  const float* bc_o = (const float*)d_in[16];
  const float* Wl_o = (const float*)d_in[17];
  const float* bl_o = (const float*)d_in[18];

  const int E = in_sizes[2];
  const int n = in_sizes[0] / 512;  // 30000
  const int NB = (n + 255) / 256;   // 118

  // workspace layout
  char* ws = (char*)d_ws;
  bf16*  ybf   = (bf16*)ws;                      // MPAD*512*2  = 30,801,920
  float* dinv  = (float*)(ws + 30801920);        // 120,000
  bf16*  Wt    = (bf16*)(ws + 30924800);         // 3*512*512*2 = 1,572,864
  float* bcomb = (float*)(ws + 32497664);        // 6,144
  int*   bsum  = (int*)(ws + 32503808);          // 512
  (void)ws_size;

  // scratch inside d_out (184.3MB; all dead before k_gemm's epilogue writes)
  char* ob = (char*)d_out;
  float* out   = (float*)d_out;
  bf16*  xbf   = (bf16*)ob;                  // [0, 30,720,000)
  int*   srcs  = (int*)(ob + 30720000);      // 1,920,000
  float* norms = (float*)(ob + 32640000);    // 1,920,000
  int*   cnts  = (int*)(ob + 34560000);      // 120,000
  int*   offs  = (int*)(ob + 34680000);      // 120,016 (n+1 ints)
  int*   curs  = (int*)(ob + 34800016);      // 120,000
  (void)out_size; (void)n_in;

  k_init<<<NB, 256, 0, stream>>>(dinv, cnts, curs, n);
  k_pre<<<(E + 255) / 256, 256, 0, stream>>>(ei, ew, dinv, cnts, E);
  k_dinv<<<NB, 256, 0, stream>>>(dinv, n);
  k_bsum<<<NB, 256, 0, stream>>>(cnts, bsum, n);
  k_bscan<<<1, 128, 0, stream>>>(bsum, NB);
  k_offs<<<NB, 256, 0, stream>>>(cnts, bsum, offs, n, E);
  k_scatter<<<(E + 255) / 256, 256, 0, stream>>>(ei, ew, dinv, offs, curs, srcs, norms, E);
  k_xbf<<<(n * 512 / 8 + 255) / 256, 256, 0, stream>>>(x, xbf, n * 512 / 8);
  k_agg<<<(MPAD * 64 + 255) / 256, 256, 0, stream>>>(offs, srcs, norms, x, dinv, xbf, ybf);
  k_wcomb<<<dim3(8, 8, 3), 256, 0, stream>>>(Wc_i, Wl_i, Wc_g, Wl_g, Wc_o, Wl_o, Wt);
  k_bcomb3<<<24, 256, 0, stream>>>(bc_i, bl_i, Wl_i, bc_g, bl_g, Wl_g, bc_o, bl_o, Wl_o, bcomb);
  k_gemm<<<1880, 256, 0, stream>>>(ybf, Wt, bcomb, out);
}